// Round 1
// baseline (647.086 us; speedup 1.0000x reference)
//
#include <hip/hip_runtime.h>

// ---------------- degree / norm ----------------

__global__ void deg_init_kernel(float* __restrict__ deg, int N) {
    int i = blockIdx.x * blockDim.x + threadIdx.x;
    if (i < N) deg[i] = 1.0f;  // self-loop
}

__global__ void deg_count_kernel(const int* __restrict__ dst, float* __restrict__ deg, int E) {
    int e = blockIdx.x * blockDim.x + threadIdx.x;
    if (e < E) atomicAdd(&deg[dst[e]], 1.0f);
}

__global__ void rsqrt_kernel(float* __restrict__ deg, int N) {
    int i = blockIdx.x * blockDim.x + threadIdx.x;
    if (i < N) deg[i] = rsqrtf(deg[i]);
}

// ---------------- dense X(M x 64) @ W(64 x OUTD) ----------------

template <int OUTD>
__global__ void gemm_kernel(const float* __restrict__ X, const float* __restrict__ W,
                            float* __restrict__ H, int M) {
    constexpr int K    = 64;
    constexpr int ROWS = 1024 / OUTD;     // 16 rows (OUTD=64) / 32 rows (OUTD=32)
    __shared__ float ws[K][OUTD];
    __shared__ float xs[ROWS][K + 1];     // +1 pad

    const int tid = threadIdx.x;
    for (int i = tid; i < K * OUTD; i += 256)
        ws[i / OUTD][i % OUTD] = W[i];

    const int rowBase = blockIdx.x * ROWS;
    for (int i = tid; i < ROWS * K; i += 256) {
        int r = i >> 6, c = i & 63;
        int gr = rowBase + r;
        xs[r][c] = (gr < M) ? X[(size_t)gr * K + c] : 0.0f;
    }
    __syncthreads();

    const int col = tid % OUTD;
    const int r0  = tid / OUTD;
    constexpr int NT_ROWS = 256 / OUTD;
    for (int r = r0; r < ROWS; r += NT_ROWS) {
        int gr = rowBase + r;
        if (gr >= M) break;
        float acc = 0.0f;
#pragma unroll
        for (int k = 0; k < K; ++k)
            acc += xs[r][k] * ws[k][col];
        H[(size_t)gr * OUTD + col] = acc;
    }
}

// ---------------- self-loop contribution + bias (initializes out) ----------------

template <int D>
__global__ void self_bias_kernel(const float* __restrict__ H, const float* __restrict__ dinv,
                                 const float* __restrict__ bias, float* __restrict__ out, int N) {
    long long t = (long long)blockIdx.x * blockDim.x + threadIdx.x;
    if (t < (long long)N * D) {
        int i = (int)(t / D);
        int d = (int)(t % D);
        float di = dinv[i];
        out[t] = H[t] * di * di + bias[d];
    }
}

// ---------------- edge aggregation: out[dst] += H[src] * dinv[src]*dinv[dst] ----------------

template <int D>
__global__ void agg_edges_kernel(const float* __restrict__ H, const int* __restrict__ src,
                                 const int* __restrict__ dst, const float* __restrict__ dinv,
                                 float* __restrict__ out, int E) {
    long long t = (long long)blockIdx.x * blockDim.x + threadIdx.x;
    if (t < (long long)E * D) {
        int e = (int)(t / D);
        int d = (int)(t & (D - 1));
        int s = src[e];
        int q = dst[e];
        float nrm = dinv[s] * dinv[q];
        atomicAdd(&out[(size_t)q * D + d], H[(size_t)s * D + d] * nrm);
    }
}

__global__ void relu_kernel(float* __restrict__ x, long long n) {
    long long t = (long long)blockIdx.x * blockDim.x + threadIdx.x;
    if (t < n) x[t] = fmaxf(x[t], 0.0f);
}

// ---------------- launch ----------------

extern "C" void kernel_launch(void* const* d_in, const int* in_sizes, int n_in,
                              void* d_out, int out_size, void* d_ws, size_t ws_size,
                              hipStream_t stream) {
    const float* x  = (const float*)d_in[0];
    const int*   ei = (const int*)d_in[1];
    const float* W1 = (const float*)d_in[2];
    const float* b1 = (const float*)d_in[3];
    const float* W2 = (const float*)d_in[4];
    const float* b2 = (const float*)d_in[5];
    float* out = (float*)d_out;

    const int N = in_sizes[0] / 64;   // 100000
    const int E = in_sizes[1] / 2;    // 1200000
    const int* src = ei;
    const int* dst = ei + E;

    float* ws   = (float*)d_ws;
    float* dinv = ws;                          // N floats
    float* h    = ws + 100032;                 // N*64 floats (reused as h2: N*32)
    float* out1 = h + (size_t)N * 64;          // N*64 floats

    const int T = 256;

    // degrees -> dinv
    deg_init_kernel<<<(N + T - 1) / T, T, 0, stream>>>(dinv, N);
    deg_count_kernel<<<(E + T - 1) / T, T, 0, stream>>>(dst, dinv, E);
    rsqrt_kernel<<<(N + T - 1) / T, T, 0, stream>>>(dinv, N);

    // layer 1: h = x @ W1
    gemm_kernel<64><<<(N + 15) / 16, T, 0, stream>>>(x, W1, h, N);
    long long n1 = (long long)N * 64;
    self_bias_kernel<64><<<(unsigned)((n1 + T - 1) / T), T, 0, stream>>>(h, dinv, b1, out1, N);
    agg_edges_kernel<64><<<(unsigned)(((long long)E * 64 + T - 1) / T), T, 0, stream>>>(
        h, src, dst, dinv, out1, E);
    relu_kernel<<<(unsigned)((n1 + T - 1) / T), T, 0, stream>>>(out1, n1);

    // layer 2: h2 = relu_out @ W2  (h2 stored in h buffer)
    gemm_kernel<32><<<(N + 31) / 32, T, 0, stream>>>(out1, W2, h, N);
    long long n2 = (long long)N * 32;
    self_bias_kernel<32><<<(unsigned)((n2 + T - 1) / T), T, 0, stream>>>(h, dinv, b2, out, N);
    agg_edges_kernel<32><<<(unsigned)(((long long)E * 32 + T - 1) / T), T, 0, stream>>>(
        h, src, dst, dinv, out, E);
}

// Round 2
// 434.751 us; speedup vs baseline: 1.4884x; 1.4884x over previous
//
#include <hip/hip_runtime.h>

// ---------------- histogram of dst (in-degree) ----------------

__global__ void hist_kernel(const int* __restrict__ dst, int* __restrict__ counts, int E) {
    int e = blockIdx.x * blockDim.x + threadIdx.x;
    if (e < E) atomicAdd(&counts[dst[e]], 1);
}

// ---------------- 3-phase exclusive scan over counts[N] ----------------

__global__ void scan1_kernel(const int* __restrict__ counts, int* __restrict__ offs,
                             int* __restrict__ bsums, int N) {
    __shared__ int lds[256];
    int tid = threadIdx.x;
    int base = blockIdx.x * 1024 + tid * 4;
    int c0 = (base + 0 < N) ? counts[base + 0] : 0;
    int c1 = (base + 1 < N) ? counts[base + 1] : 0;
    int c2 = (base + 2 < N) ? counts[base + 2] : 0;
    int c3 = (base + 3 < N) ? counts[base + 3] : 0;
    int tsum = c0 + c1 + c2 + c3;
    lds[tid] = tsum;
    __syncthreads();
    for (int off = 1; off < 256; off <<= 1) {
        int v = (tid >= off) ? lds[tid - off] : 0;
        __syncthreads();
        lds[tid] += v;
        __syncthreads();
    }
    int texc = lds[tid] - tsum;  // exclusive prefix within block
    if (base + 0 < N) offs[base + 0] = texc;
    if (base + 1 < N) offs[base + 1] = texc + c0;
    if (base + 2 < N) offs[base + 2] = texc + c0 + c1;
    if (base + 3 < N) offs[base + 3] = texc + c0 + c1 + c2;
    if (tid == 255) bsums[blockIdx.x] = lds[255];
}

__global__ void scan2_kernel(int* __restrict__ bsums, int NB) {
    __shared__ int lds[256];
    int tid = threadIdx.x;
    int v = (tid < NB) ? bsums[tid] : 0;
    lds[tid] = v;
    __syncthreads();
    for (int off = 1; off < 256; off <<= 1) {
        int x = (tid >= off) ? lds[tid - off] : 0;
        __syncthreads();
        lds[tid] += x;
        __syncthreads();
    }
    if (tid < NB) bsums[tid] = lds[tid] - v;  // exclusive
}

__global__ void finalize_kernel(int* __restrict__ offs, int* __restrict__ cursor,
                                const int* __restrict__ bsums, const int* __restrict__ counts,
                                float* __restrict__ dinv, int N) {
    int i = blockIdx.x * blockDim.x + threadIdx.x;
    if (i < N) {
        int o = offs[i] + bsums[i >> 10];
        offs[i] = o;
        cursor[i] = o;
        dinv[i] = rsqrtf((float)counts[i] + 1.0f);  // +1 self-loop
    }
}

// ---------------- scatter edges into CSR (sorted by dst) ----------------

__global__ void scatter_kernel(const int* __restrict__ src, const int* __restrict__ dst,
                               int* __restrict__ cursor, int* __restrict__ ssrc, int E) {
    int e = blockIdx.x * blockDim.x + threadIdx.x;
    if (e < E) {
        int p = atomicAdd(&cursor[dst[e]], 1);
        ssrc[p] = src[e];
    }
}

// ---------------- dense X(M x 64) @ W(64 x OUTD) ----------------

template <int OUTD>
__global__ void gemm_kernel(const float* __restrict__ X, const float* __restrict__ W,
                            float* __restrict__ H, int M) {
    constexpr int K    = 64;
    constexpr int ROWS = 1024 / OUTD;
    __shared__ float ws[K][OUTD];
    __shared__ float xs[ROWS][K + 1];

    const int tid = threadIdx.x;
    for (int i = tid; i < K * OUTD; i += 256)
        ws[i / OUTD][i % OUTD] = W[i];

    const int rowBase = blockIdx.x * ROWS;
    for (int i = tid; i < ROWS * K; i += 256) {
        int r = i >> 6, c = i & 63;
        int gr = rowBase + r;
        xs[r][c] = (gr < M) ? X[(size_t)gr * K + c] : 0.0f;
    }
    __syncthreads();

    const int col = tid % OUTD;
    const int r0  = tid / OUTD;
    constexpr int NT_ROWS = 256 / OUTD;
    for (int r = r0; r < ROWS; r += NT_ROWS) {
        int gr = rowBase + r;
        if (gr >= M) break;
        float acc = 0.0f;
#pragma unroll
        for (int k = 0; k < K; ++k)
            acc += xs[r][k] * ws[k][col];
        H[(size_t)gr * OUTD + col] = acc;
    }
}

// ---------------- CSR aggregation, D=64: one wave per node ----------------
// out[n][d] = dinv[n] * ( sum_{s in row n} h[s][d]*dinv[s]  +  h[n][d]*dinv[n] ) + bias[d]

template <bool RELU>
__global__ void agg64_kernel(const float* __restrict__ h, const int* __restrict__ ssrc,
                             const int* __restrict__ offs, const int* __restrict__ counts,
                             const float* __restrict__ dinv, const float* __restrict__ bias,
                             float* __restrict__ out, int N) {
    int wid  = threadIdx.x >> 6;
    int lane = threadIdx.x & 63;
    int node = blockIdx.x * 4 + wid;
    if (node >= N) return;
    int beg = offs[node], cnt = counts[node];
    float dd   = dinv[node];
    float b    = bias[lane];
    float self = h[(size_t)node * 64 + lane];
    float acc  = 0.0f;
    for (int base = 0; base < cnt; base += 64) {
        int rem = cnt - base;
        if (rem > 64) rem = 64;
        int idx = 0;
        float dv = 0.0f;
        if (lane < rem) {
            idx = ssrc[beg + base + lane];
            dv  = dinv[idx];
        }
        for (int k = 0; k < rem; ++k) {
            int s    = __shfl(idx, k, 64);
            float nv = __shfl(dv, k, 64);
            acc += h[(size_t)s * 64 + lane] * nv;
        }
    }
    float r = dd * (acc + self * dd) + b;
    if (RELU) r = fmaxf(r, 0.0f);
    out[(size_t)node * 64 + lane] = r;
}

// ---------------- CSR aggregation, D=32: two nodes per wave ----------------

__global__ void agg32_kernel(const float* __restrict__ h, const int* __restrict__ ssrc,
                             const int* __restrict__ offs, const int* __restrict__ counts,
                             const float* __restrict__ dinv, const float* __restrict__ bias,
                             float* __restrict__ out, int N) {
    int wid  = threadIdx.x >> 6;
    int lane = threadIdx.x & 63;
    int half = lane >> 5;
    int dim  = lane & 31;
    int node = blockIdx.x * 8 + wid * 2 + half;
    if (node >= N) return;
    int beg = offs[node], cnt = counts[node];
    float dd   = dinv[node];
    float b    = bias[dim];
    float self = h[(size_t)node * 32 + dim];
    float acc  = 0.0f;
    for (int base = 0; base < cnt; base += 32) {
        int rem = cnt - base;
        if (rem > 32) rem = 32;
        int idx = 0;
        float dv = 0.0f;
        if (dim < rem) {
            idx = ssrc[beg + base + dim];
            dv  = dinv[idx];
        }
        for (int k = 0; k < rem; ++k) {
            int s    = __shfl(idx, half * 32 + k, 64);
            float nv = __shfl(dv, half * 32 + k, 64);
            acc += h[(size_t)s * 32 + dim] * nv;
        }
    }
    out[(size_t)node * 32 + dim] = dd * (acc + self * dd) + b;
}

// ---------------- launch ----------------

extern "C" void kernel_launch(void* const* d_in, const int* in_sizes, int n_in,
                              void* d_out, int out_size, void* d_ws, size_t ws_size,
                              hipStream_t stream) {
    const float* x  = (const float*)d_in[0];
    const int*   ei = (const int*)d_in[1];
    const float* W1 = (const float*)d_in[2];
    const float* b1 = (const float*)d_in[3];
    const float* W2 = (const float*)d_in[4];
    const float* b2 = (const float*)d_in[5];
    float* out = (float*)d_out;

    const int N = in_sizes[0] / 64;   // 100000
    const int E = in_sizes[1] / 2;    // 1200000
    const int* src = ei;
    const int* dst = ei + E;

    const int Npad = (N + 1023) & ~1023;  // 100352

    // workspace layout (4-byte elements)
    int*   counts = (int*)d_ws;               // Npad
    int*   offs   = counts + Npad;            // Npad
    int*   cursor = offs + Npad;              // Npad
    float* dinv   = (float*)(cursor + Npad);  // Npad
    int*   bsums  = (int*)(dinv + Npad);      // 256
    int*   ssrc   = bsums + 256;              // E
    float* h      = (float*)(ssrc + E);       // N*64 (reused as h2: N*32)
    float* out1   = h + (size_t)N * 64;       // N*64

    const int T  = 256;
    const int NB = (N + 1023) / 1024;         // 98 <= 256

    // build CSR by dst + dinv
    hipMemsetAsync(counts, 0, (size_t)N * sizeof(int), stream);
    hist_kernel<<<(E + T - 1) / T, T, 0, stream>>>(dst, counts, E);
    scan1_kernel<<<NB, T, 0, stream>>>(counts, offs, bsums, N);
    scan2_kernel<<<1, T, 0, stream>>>(bsums, NB);
    finalize_kernel<<<(N + T - 1) / T, T, 0, stream>>>(offs, cursor, bsums, counts, dinv, N);
    scatter_kernel<<<(E + T - 1) / T, T, 0, stream>>>(src, dst, cursor, ssrc, E);

    // layer 1
    gemm_kernel<64><<<(N + 15) / 16, T, 0, stream>>>(x, W1, h, N);
    agg64_kernel<true><<<(N + 3) / 4, T, 0, stream>>>(h, ssrc, offs, counts, dinv, b1, out1, N);

    // layer 2 (h2 reuses h buffer)
    gemm_kernel<32><<<(N + 31) / 32, T, 0, stream>>>(out1, W2, h, N);
    agg32_kernel<<<(N + 7) / 8, T, 0, stream>>>(h, ssrc, offs, counts, dinv, b2, out, N);
}

// Round 3
// 385.069 us; speedup vs baseline: 1.6804x; 1.1290x over previous
//
#include <hip/hip_runtime.h>
#include <hip/hip_fp16.h>

// ---------------- histogram of dst (in-degree) ----------------

__global__ void hist_kernel(const int* __restrict__ dst, int* __restrict__ counts, int E) {
    int e = blockIdx.x * blockDim.x + threadIdx.x;
    if (e < E) atomicAdd(&counts[dst[e]], 1);
}

// ---------------- 3-phase exclusive scan over counts[N] ----------------

__global__ void scan1_kernel(const int* __restrict__ counts, int* __restrict__ offs,
                             int* __restrict__ bsums, int N) {
    __shared__ int lds[256];
    int tid = threadIdx.x;
    int base = blockIdx.x * 1024 + tid * 4;
    int c0 = (base + 0 < N) ? counts[base + 0] : 0;
    int c1 = (base + 1 < N) ? counts[base + 1] : 0;
    int c2 = (base + 2 < N) ? counts[base + 2] : 0;
    int c3 = (base + 3 < N) ? counts[base + 3] : 0;
    int tsum = c0 + c1 + c2 + c3;
    lds[tid] = tsum;
    __syncthreads();
    for (int off = 1; off < 256; off <<= 1) {
        int v = (tid >= off) ? lds[tid - off] : 0;
        __syncthreads();
        lds[tid] += v;
        __syncthreads();
    }
    int texc = lds[tid] - tsum;
    if (base + 0 < N) offs[base + 0] = texc;
    if (base + 1 < N) offs[base + 1] = texc + c0;
    if (base + 2 < N) offs[base + 2] = texc + c0 + c1;
    if (base + 3 < N) offs[base + 3] = texc + c0 + c1 + c2;
    if (tid == 255) bsums[blockIdx.x] = lds[255];
}

__global__ void scan2_kernel(int* __restrict__ bsums, int NB) {
    __shared__ int lds[256];
    int tid = threadIdx.x;
    int v = (tid < NB) ? bsums[tid] : 0;
    lds[tid] = v;
    __syncthreads();
    for (int off = 1; off < 256; off <<= 1) {
        int x = (tid >= off) ? lds[tid - off] : 0;
        __syncthreads();
        lds[tid] += x;
        __syncthreads();
    }
    if (tid < NB) bsums[tid] = lds[tid] - v;
}

__global__ void finalize_kernel(int* __restrict__ offs, int* __restrict__ cursor,
                                const int* __restrict__ bsums, const int* __restrict__ counts,
                                float* __restrict__ dinv, int N) {
    int i = blockIdx.x * blockDim.x + threadIdx.x;
    if (i < N) {
        int o = offs[i] + bsums[i >> 10];
        offs[i] = o;
        cursor[i] = o;
        dinv[i] = rsqrtf((float)counts[i] + 1.0f);  // +1 self-loop
    }
}

// ---------------- scatter edges into CSR; pack (src, dinv[src]) in 8B ----------------

__global__ void scatter_kernel(const int* __restrict__ src, const int* __restrict__ dst,
                               const float* __restrict__ dinv, int* __restrict__ cursor,
                               unsigned long long* __restrict__ sedge, int E) {
    int e = blockIdx.x * blockDim.x + threadIdx.x;
    if (e < E) {
        int s = src[e];
        int p = atomicAdd(&cursor[dst[e]], 1);
        float dv = dinv[s];
        sedge[p] = ((unsigned long long)__float_as_uint(dv) << 32) | (unsigned)s;
    }
}

// ---------------- dense X(M x 64) @ W(64 x OUTD) -> fp16 ----------------

__device__ inline float cvt_f(float v) { return v; }
__device__ inline float cvt_f(__half v) { return __half2float(v); }

template <int OUTD, typename TIN>
__global__ void gemm_kernel(const TIN* __restrict__ X, const float* __restrict__ W,
                            __half* __restrict__ H, int M) {
    constexpr int K    = 64;
    constexpr int ROWS = 1024 / OUTD;
    __shared__ float ws[K][OUTD];
    __shared__ float xs[ROWS][K + 1];

    const int tid = threadIdx.x;
    for (int i = tid; i < K * OUTD; i += 256)
        ws[i / OUTD][i % OUTD] = W[i];

    const int rowBase = blockIdx.x * ROWS;
    for (int i = tid; i < ROWS * K; i += 256) {
        int r = i >> 6, c = i & 63;
        int gr = rowBase + r;
        xs[r][c] = (gr < M) ? cvt_f(X[(size_t)gr * K + c]) : 0.0f;
    }
    __syncthreads();

    const int col = tid % OUTD;
    const int r0  = tid / OUTD;
    constexpr int NT_ROWS = 256 / OUTD;
    for (int r = r0; r < ROWS; r += NT_ROWS) {
        int gr = rowBase + r;
        if (gr >= M) break;
        float acc = 0.0f;
#pragma unroll
        for (int k = 0; k < K; ++k)
            acc += xs[r][k] * ws[k][col];
        H[(size_t)gr * OUTD + col] = __float2half(acc);
    }
}

// ---------------- CSR aggregation, D=64 fp16: wave/node, 2 edges per step ----------------
// out[n][:] = relu( dinv[n]*( sum h[s]*dinv[s] + h[n]*dinv[n] ) + bias )  -> fp16

__global__ void agg64_kernel(const __half2* __restrict__ hrow, const unsigned long long* __restrict__ sedge,
                             const int* __restrict__ offs, const int* __restrict__ counts,
                             const float* __restrict__ dinv, const float* __restrict__ bias,
                             __half2* __restrict__ outrow, int N) {
    int wid  = threadIdx.x >> 6;
    int lane = threadIdx.x & 63;
    int node = blockIdx.x * 4 + wid;
    if (node >= N) return;
    int hf = lane >> 5;      // which of 2 edges per step
    int l  = lane & 31;      // half2 index (dims 2l, 2l+1)
    int beg = offs[node], cnt = counts[node];
    float ax = 0.0f, ay = 0.0f;
    for (int base = 0; base < cnt; base += 64) {
        int rem = cnt - base;
        if (rem > 64) rem = 64;
        unsigned long long pk = 0;
        if (lane < rem) pk = sedge[beg + base + lane];
        int   idx = (int)(unsigned)(pk & 0xffffffffull);
        float dv  = __uint_as_float((unsigned)(pk >> 32));
        for (int k = 0; k < rem; k += 2) {
            int e = k + hf;
            int   s  = __shfl(idx, e, 64);
            float nv = __shfl(dv, e, 64);
            if (e < rem) {
                float2 f = __half22float2(hrow[(size_t)s * 32 + l]);
                ax = fmaf(f.x, nv, ax);
                ay = fmaf(f.y, nv, ay);
            }
        }
    }
    ax += __shfl_xor(ax, 32, 64);
    ay += __shfl_xor(ay, 32, 64);
    if (hf == 0) {
        float dd = dinv[node];
        float2 sf = __half22float2(hrow[(size_t)node * 32 + l]);
        float rx = fmaxf(dd * (ax + sf.x * dd) + bias[2 * l],     0.0f);
        float ry = fmaxf(dd * (ay + sf.y * dd) + bias[2 * l + 1], 0.0f);
        outrow[(size_t)node * 32 + l] = __floats2half2_rn(rx, ry);
    }
}

// ---------------- CSR aggregation, D=32 fp16: wave/node, 4 edges per step -> fp32 out ----------------

__global__ void agg32_kernel(const __half2* __restrict__ hrow, const unsigned long long* __restrict__ sedge,
                             const int* __restrict__ offs, const int* __restrict__ counts,
                             const float* __restrict__ dinv, const float* __restrict__ bias,
                             float2* __restrict__ outrow, int N) {
    int wid  = threadIdx.x >> 6;
    int lane = threadIdx.x & 63;
    int node = blockIdx.x * 4 + wid;
    if (node >= N) return;
    int q = lane >> 4;       // which of 4 edges per step
    int l = lane & 15;       // half2 index (dims 2l, 2l+1)
    int beg = offs[node], cnt = counts[node];
    float ax = 0.0f, ay = 0.0f;
    for (int base = 0; base < cnt; base += 64) {
        int rem = cnt - base;
        if (rem > 64) rem = 64;
        unsigned long long pk = 0;
        if (lane < rem) pk = sedge[beg + base + lane];
        int   idx = (int)(unsigned)(pk & 0xffffffffull);
        float dv  = __uint_as_float((unsigned)(pk >> 32));
        for (int k = 0; k < rem; k += 4) {
            int e = k + q;
            int   s  = __shfl(idx, e, 64);
            float nv = __shfl(dv, e, 64);
            if (e < rem) {
                float2 f = __half22float2(hrow[(size_t)s * 16 + l]);
                ax = fmaf(f.x, nv, ax);
                ay = fmaf(f.y, nv, ay);
            }
        }
    }
    ax += __shfl_xor(ax, 16, 64);
    ay += __shfl_xor(ay, 16, 64);
    ax += __shfl_xor(ax, 32, 64);
    ay += __shfl_xor(ay, 32, 64);
    if (q == 0) {
        float dd = dinv[node];
        float2 sf = __half22float2(hrow[(size_t)node * 16 + l]);
        float2 r;
        r.x = dd * (ax + sf.x * dd) + bias[2 * l];
        r.y = dd * (ay + sf.y * dd) + bias[2 * l + 1];
        outrow[(size_t)node * 16 + l] = r;
    }
}

// ---------------- launch ----------------

extern "C" void kernel_launch(void* const* d_in, const int* in_sizes, int n_in,
                              void* d_out, int out_size, void* d_ws, size_t ws_size,
                              hipStream_t stream) {
    const float* x  = (const float*)d_in[0];
    const int*   ei = (const int*)d_in[1];
    const float* W1 = (const float*)d_in[2];
    const float* b1 = (const float*)d_in[3];
    const float* W2 = (const float*)d_in[4];
    const float* b2 = (const float*)d_in[5];
    float* out = (float*)d_out;

    const int N = in_sizes[0] / 64;   // 100000
    const int E = in_sizes[1] / 2;    // 1200000
    const int* src = ei;
    const int* dst = ei + E;

    const int Npad = (N + 1023) & ~1023;  // 100352

    // workspace layout
    int*   counts = (int*)d_ws;               // Npad ints
    int*   offs   = counts + Npad;
    int*   cursor = offs + Npad;
    float* dinv   = (float*)(cursor + Npad);
    int*   bsums  = (int*)(dinv + Npad);      // 256 ints
    unsigned long long* sedge = (unsigned long long*)(bsums + 256);  // E * 8B (8B-aligned: 4*Npad+256 ints is even)
    __half* h    = (__half*)(sedge + E);      // N*64 fp16 (reused as h2: N*32)
    __half* out1 = h + (size_t)N * 64;        // N*64 fp16

    const int T  = 256;
    const int NB = (N + 1023) / 1024;         // 98

    // build CSR by dst + dinv
    hipMemsetAsync(counts, 0, (size_t)N * sizeof(int), stream);
    hist_kernel<<<(E + T - 1) / T, T, 0, stream>>>(dst, counts, E);
    scan1_kernel<<<NB, T, 0, stream>>>(counts, offs, bsums, N);
    scan2_kernel<<<1, T, 0, stream>>>(bsums, NB);
    finalize_kernel<<<(N + T - 1) / T, T, 0, stream>>>(offs, cursor, bsums, counts, dinv, N);
    scatter_kernel<<<(E + T - 1) / T, T, 0, stream>>>(src, dst, dinv, cursor, sedge, E);

    // layer 1
    gemm_kernel<64, float><<<(N + 15) / 16, T, 0, stream>>>(x, W1, h, N);
    agg64_kernel<<<(N + 3) / 4, T, 0, stream>>>((const __half2*)h, sedge, offs, counts, dinv, b1,
                                                (__half2*)out1, N);

    // layer 2 (h2 reuses h buffer)
    gemm_kernel<32, __half><<<(N + 31) / 32, T, 0, stream>>>(out1, W2, h, N);
    agg32_kernel<<<(N + 3) / 4, T, 0, stream>>>((const __half2*)h, sedge, offs, counts, dinv, b2,
                                                (float2*)out, N);
}